// Round 4
// baseline (11199.957 us; speedup 1.0000x reference)
//
#include <hip/hip_runtime.h>
#include <hip/hip_bf16.h>
#include <stdint.h>

// LCA on MI355X, round 4: dtype-agnostic (device-side fp32/bf16 sniff) +
// residual-form iteration  du = (x - a@w^T)@w + a - u  (no b, no g, no a
// ping-pong). ws = u f32 (67.1MB) + r bf16 (13.1MB) + wT (3.3MB) + wB (3.2MB)
// + flag = 86.7MB. 'a' (bf16) lives in d_out at byte off 8192*784*2 (= the
// bf16 a-region: zero-copy if out is bf16; 2-pass race-free expand if fp32).

typedef __bf16 bf16_t;
typedef float f32x4 __attribute__((ext_vector_type(4)));
typedef __bf16 bf16x8 __attribute__((ext_vector_type(8)));
typedef int int4v __attribute__((ext_vector_type(4)));

#define BM 128
#define BN 128
#define BK 32

static __device__ __forceinline__ f32x4 mfma16(int4v a, int4v b, f32x4 c) {
    return __builtin_amdgcn_mfma_f32_16x16x32_bf16(
        __builtin_bit_cast(bf16x8, a), __builtin_bit_cast(bf16x8, b), c, 0, 0, 0);
}

// flag=1 iff inputs are fp32. Even-index halfwords of w: bf16 data -> real
// bf16 values (|w|<=1, exp field <= 0x7f); fp32 data -> low mantissa bits
// (uniform, ~49% have exp field >= 0x82).
__global__ void sniff(const uint16_t* __restrict__ wh, int* __restrict__ flag) {
    __shared__ int cnt;
    if (threadIdx.x == 0) cnt = 0;
    __syncthreads();
    int c = 0;
    for (int t = threadIdx.x; t < 4096; t += 256) {
        uint16_t h = wh[(size_t)2 * t * 97];   // max idx 794430 < 784*2048
        c += (((h >> 7) & 0xFF) >= 0x82);
    }
    atomicAdd(&cnt, c);
    __syncthreads();
    if (threadIdx.x == 0) flag[0] = (cnt > 256) ? 1 : 0;
}

__global__ void fill0(int4v* __restrict__ p, long n16) {
    long i = (long)blockIdx.x * 256 + threadIdx.x;
    if (i < n16) p[i] = (int4v){0, 0, 0, 0};
}

// wB[k,j] = bf16(w[k,j]) for k<784;  wT[j,k] = wB[k,j], zero-padded to k<800
__global__ void build_w(const void* __restrict__ w, bf16_t* __restrict__ wT,
                        bf16_t* __restrict__ wB, const int* __restrict__ flag) {
    const int k = blockIdx.x * 256 + threadIdx.x;
    const int j = blockIdx.y;
    if (k >= 800) return;
    bf16_t v = (bf16_t)0.0f;
    if (k < 784) {
        v = flag[0] ? (bf16_t)((const float*)w)[(size_t)k * 2048 + j]
                    : ((const bf16_t*)w)[(size_t)k * 2048 + j];
        wB[(size_t)k * 2048 + j] = v;
    }
    wT[(size_t)j * 800 + k] = v;
}

// NT-GEMM  C[i,j] = sum_k A[i,k]*B[j,k].
// MODE 0 (R):    r[gm,gn] = x[gm,gn] - C   (gn<N; x dtype per flag)
// MODE 1 (STEP): uo=U; ao=relu(uo-.3); un=uo+0.01*(C+ao-uo); U=un; a=relu(un-.3)
// MODE 2 (REC):  Out[gm,gn] = bf16(C)  (gn<N)
template <int MODE, bool CLAMPN>
__global__ __launch_bounds__(256, 2) void gemm_nt(
    const bf16_t* __restrict__ A, const bf16_t* __restrict__ B,
    int N, int K, int lda, int ldb,
    const void* __restrict__ Xin, float* __restrict__ U,
    bf16_t* __restrict__ Out, int ldo, const int* __restrict__ flag)
{
    __shared__ __align__(16) bf16_t sA[BM * BK];
    __shared__ __align__(16) bf16_t sB[BN * BK];

    const int tid  = threadIdx.x;
    const int lane = tid & 63;
    const int wave = tid >> 6;
    const int wm   = wave >> 1;
    const int wn   = wave & 1;
    const int bm   = blockIdx.x * BM;
    const int bn   = blockIdx.y * BN;

    f32x4 acc[4][4];
#pragma unroll
    for (int i = 0; i < 4; ++i)
#pragma unroll
        for (int j = 0; j < 4; ++j) acc[i][j] = (f32x4){0.f, 0.f, 0.f, 0.f};

    const int s_row = tid >> 2;   // 0..63
    const int s_cc  = tid & 3;    // 16B chunk in a 32-elem row

    int rB0 = bn + s_row, rB1 = bn + 64 + s_row;
    if (CLAMPN) { rB0 = min(rB0, N - 1); rB1 = min(rB1, N - 1); }
    const bf16_t* gA0 = A + (size_t)(bm + s_row) * lda + s_cc * 8;
    const bf16_t* gA1 = A + (size_t)(bm + 64 + s_row) * lda + s_cc * 8;
    const bf16_t* gB0 = B + (size_t)rB0 * ldb + s_cc * 8;
    const bf16_t* gB1 = B + (size_t)rB1 * ldb + s_cc * 8;

    bf16_t* dA0 = sA + (size_t)tid * 8;
    bf16_t* dA1 = sA + (size_t)(256 + tid) * 8;
    bf16_t* dB0 = sB + (size_t)tid * 8;
    bf16_t* dB1 = sB + (size_t)(256 + tid) * 8;

    const int mrow = lane & 15;
    const int q    = lane >> 4;

    for (int k0 = 0; k0 < K; k0 += BK) {
        const bf16x8 ra0 = *(const bf16x8*)(gA0 + k0);
        const bf16x8 ra1 = *(const bf16x8*)(gA1 + k0);
        const bf16x8 rb0 = *(const bf16x8*)(gB0 + k0);
        const bf16x8 rb1 = *(const bf16x8*)(gB1 + k0);
        __syncthreads();
        *(bf16x8*)dA0 = ra0;
        *(bf16x8*)dA1 = ra1;
        *(bf16x8*)dB0 = rb0;
        *(bf16x8*)dB1 = rb1;
        __syncthreads();

        int4v af[4], bf[4];
        const bf16_t* pa = sA + ((wm * 64 + mrow) * BK + q * 8);
        const bf16_t* pb = sB + ((wn * 64 + mrow) * BK + q * 8);
#pragma unroll
        for (int t = 0; t < 4; ++t) {
            af[t] = *(const int4v*)(pa + t * 16 * BK);
            bf[t] = *(const int4v*)(pb + t * 16 * BK);
        }
#pragma unroll
        for (int mt = 0; mt < 4; ++mt)
#pragma unroll
            for (int nt = 0; nt < 4; ++nt)
                acc[mt][nt] = mfma16(af[mt], bf[nt], acc[mt][nt]);
    }

    int f = 0;
    if (MODE == 0) f = flag[0];

    // C/D layout: col = lane&15, row = (lane>>4)*4 + r   [m89/m91]
    const int coln = lane & 15;
    const int rq   = lane >> 4;
#pragma unroll
    for (int mt = 0; mt < 4; ++mt) {
#pragma unroll
        for (int r = 0; r < 4; ++r) {
            const int gm = bm + wm * 64 + mt * 16 + rq * 4 + r;
#pragma unroll
            for (int nt = 0; nt < 4; ++nt) {
                const int gn = bn + wn * 64 + nt * 16 + coln;
                const float c = acc[mt][nt][r];
                if (MODE == 0) {
                    if (gn < N) {
                        const size_t xi = (size_t)gm * N + gn;
                        const float xv = f ? ((const float*)Xin)[xi]
                                           : (float)((const bf16_t*)Xin)[xi];
                        Out[(size_t)gm * ldo + gn] = (bf16_t)(xv - c);
                    }
                } else if (MODE == 1) {
                    const size_t idx = (size_t)gm * ldo + gn;
                    const float uo = U[idx];
                    const float ao = fmaxf(uo - 0.3f, 0.0f);
                    const float un = uo + 0.01f * (c + ao - uo);
                    U[idx] = un;
                    Out[idx] = (bf16_t)fmaxf(un - 0.3f, 0.0f);
                } else {
                    if (gn < N)
                        Out[(size_t)gm * ldo + gn] = (bf16_t)c;
                }
            }
        }
    }
}

// fp32-output only: expand a (bf16, d_out scratch) into the fp32 a-region.
// Two passes with disjoint src/dst per pass (expansion-by-2 overlap split).
__global__ void a_move(const bf16_t* __restrict__ src, float* __restrict__ dst,
                       long lo, long hi, const int* __restrict__ flag) {
    if (!flag[0]) return;
    long i = lo + (long)blockIdx.x * 256 + threadIdx.x;
    if (i < hi) dst[i] = (float)src[i];
}

__global__ void recon_out(const bf16_t* __restrict__ rec, void* __restrict__ dout,
                          const int* __restrict__ flag) {
    long i = (long)blockIdx.x * 256 + threadIdx.x;
    if (i >= 6422528L) return;
    if (flag[0]) ((float*)dout)[i] = (float)rec[i];
    else         ((bf16_t*)dout)[i] = rec[i];
}

extern "C" void kernel_launch(void* const* d_in, const int* in_sizes, int n_in,
                              void* d_out, int out_size, void* d_ws, size_t ws_size,
                              hipStream_t stream) {
    const void* x = d_in[0];   // [8192, 784]  fp32 or bf16
    const void* w = d_in[1];   // [784, 2048]  fp32 or bf16
    (void)in_sizes; (void)n_in; (void)out_size; (void)ws_size;

    char* ws = (char*)d_ws;
    float*  u    = (float*)ws;                          // 67,108,864 B
    bf16_t* r    = (bf16_t*)(ws + 67108864);            // 13,107,200 B (8192x800)
    bf16_t* wT   = (bf16_t*)(ws + 80216064);            //  3,276,800 B (2048x800)
    bf16_t* wB   = (bf16_t*)(ws + 83492864);            //  3,211,264 B (784x2048)
    int*    flag = (int*)(ws + 86704128);               // total 86.7 MB
    bf16_t* aA   = (bf16_t*)((char*)d_out + 12845056);  // a scratch = bf16 a-region
    bf16_t* rec  = r;                                   // reuse r for recon temp

    sniff<<<1, 256, 0, stream>>>((const uint16_t*)w, flag);
    fill0<<<16384, 256, 0, stream>>>((int4v*)u, 4194304L);   // u = 0
    fill0<<<3200, 256, 0, stream>>>((int4v*)r, 819200L);     // r = 0 (incl. pad)
    fill0<<<8192, 256, 0, stream>>>((int4v*)aA, 2097152L);   // a = 0
    build_w<<<dim3(4, 2048), 256, 0, stream>>>(w, wT, wB, flag);

    // 99 LCA updates: r = x - a@w^T ; u += 0.01*(r@w + a - u); a = relu(u-0.3)
    for (int i = 0; i < 99; ++i) {
        gemm_nt<0, true><<<dim3(64, 7), 256, 0, stream>>>(
            aA, wB, 784, 2048, 2048, 2048, x, nullptr, r, 800, flag);
        gemm_nt<1, false><<<dim3(64, 16), 256, 0, stream>>>(
            r, wT, 2048, 800, 800, 800, nullptr, u, aA, 2048, flag);
    }

    // reconstruction = a @ w^T -> ws temp (bf16)
    gemm_nt<2, true><<<dim3(64, 7), 256, 0, stream>>>(
        aA, wB, 784, 2048, 2048, 2048, nullptr, nullptr, rec, 784, flag);

    // fp32 out: move a into fp32 a-region (race-free 2-pass split at 5,177,344)
    float* aOutF = (float*)d_out + 6422528;
    a_move<<<45312, 256, 0, stream>>>(aA, aOutF, 5177344L, 16777216L, flag);
    a_move<<<20224, 256, 0, stream>>>(aA, aOutF, 0L, 5177344L, flag);

    // recon -> d_out front, flag dtype (aA scratch dead by now in fp32 mode)
    recon_out<<<25088, 256, 0, stream>>>(rec, d_out, flag);
}

// Round 5
// 10133.331 us; speedup vs baseline: 1.1053x; 1.1053x over previous
//
#include <hip/hip_runtime.h>
#include <hip/hip_bf16.h>
#include <stdint.h>

// LCA on MI355X, round 5. Residual form: r = x - a@w^T ; u += 0.01*(r@w + a - u);
// a = relu(u - 0.3). All GEMMs NT. Changes vs round 4 (passed, 11.2 ms):
//  - MODE 0/REC use BN=64 tiles -> grid 64x13=832 blocks (was 448, latency-bound)
//  - m97-style global_load_lds width=16 staging in all GEMMs (no VALU round-trip)
// ws = u f32 (67.1MB) + r bf16 (13.1MB) + wT (3.3MB) + wB (3.2MB) + flag = 86.7MB.

typedef __bf16 bf16_t;
typedef float f32x4 __attribute__((ext_vector_type(4)));
typedef __bf16 bf16x8 __attribute__((ext_vector_type(8)));
typedef int int4v __attribute__((ext_vector_type(4)));

#define BM 128
#define BK 32

static __device__ __forceinline__ f32x4 mfma16(int4v a, int4v b, f32x4 c) {
    return __builtin_amdgcn_mfma_f32_16x16x32_bf16(
        __builtin_bit_cast(bf16x8, a), __builtin_bit_cast(bf16x8, b), c, 0, 0, 0);
}

// async global->LDS, 16B/lane; LDS dest = wave-uniform base + lane*16.
static __device__ __forceinline__ void gl_lds16(const bf16_t* gp, bf16_t* lp) {
    auto g1 = (const __attribute__((address_space(1))) uint32_t*)(uintptr_t)gp;
    auto l3 = (__attribute__((address_space(3))) uint32_t*)(uintptr_t)lp;
    __builtin_amdgcn_global_load_lds(g1, l3, 16, 0, 0);
}

// flag=1 iff inputs are fp32 (sniff even halfwords of w: fp32 mantissa bits
// look like huge-exponent bf16s; real bf16 |w|<=1 has exp field <= 0x7f).
__global__ void sniff(const uint16_t* __restrict__ wh, int* __restrict__ flag) {
    __shared__ int cnt;
    if (threadIdx.x == 0) cnt = 0;
    __syncthreads();
    int c = 0;
    for (int t = threadIdx.x; t < 4096; t += 256) {
        uint16_t h = wh[(size_t)2 * t * 97];
        c += (((h >> 7) & 0xFF) >= 0x82);
    }
    atomicAdd(&cnt, c);
    __syncthreads();
    if (threadIdx.x == 0) flag[0] = (cnt > 256) ? 1 : 0;
}

__global__ void fill0(int4v* __restrict__ p, long n16) {
    long i = (long)blockIdx.x * 256 + threadIdx.x;
    if (i < n16) p[i] = (int4v){0, 0, 0, 0};
}

// wB[k,j] = bf16(w[k,j]) for k<784;  wT[j,k] = wB[k,j], zero-padded to k<800
__global__ void build_w(const void* __restrict__ w, bf16_t* __restrict__ wT,
                        bf16_t* __restrict__ wB, const int* __restrict__ flag) {
    const int k = blockIdx.x * 256 + threadIdx.x;
    const int j = blockIdx.y;
    if (k >= 800) return;
    bf16_t v = (bf16_t)0.0f;
    if (k < 784) {
        v = flag[0] ? (bf16_t)((const float*)w)[(size_t)k * 2048 + j]
                    : ((const bf16_t*)w)[(size_t)k * 2048 + j];
        wB[(size_t)k * 2048 + j] = v;
    }
    wT[(size_t)j * 800 + k] = v;
}

// NT-GEMM  C[i,j] = sum_k A[i,k]*B[j,k].  Tile BM x BNT (BNT in {64,128}).
// MODE 0 (R):    r[gm,gn] = x[gm,gn] - C   (gn<N; x dtype per flag)
// MODE 1 (STEP): uo=U; ao=relu(uo-.3); un=uo+0.01*(C+ao-uo); U=un; a=relu(un-.3)
// MODE 2 (REC):  Out[gm,gn] = bf16(C)  (gn<N)
template <int MODE, bool CLAMPN, int BNT>
__global__ __launch_bounds__(256, 2) void gemm_nt(
    const bf16_t* __restrict__ A, const bf16_t* __restrict__ B,
    int N, int K, int lda, int ldb,
    const void* __restrict__ Xin, float* __restrict__ U,
    bf16_t* __restrict__ Out, int ldo, const int* __restrict__ flag)
{
    constexpr int NTC = BNT / 32;   // 16-wide n-tiles per wave
    __shared__ __align__(16) bf16_t sA[BM * BK];
    __shared__ __align__(16) bf16_t sB[BNT * BK];

    const int tid  = threadIdx.x;
    const int lane = tid & 63;
    const int wave = tid >> 6;
    const int wm   = wave >> 1;   // 2x2 wave grid
    const int wn   = wave & 1;
    const int bm   = blockIdx.x * BM;
    const int bn   = blockIdx.y * BNT;

    f32x4 acc[4][NTC];
#pragma unroll
    for (int i = 0; i < 4; ++i)
#pragma unroll
        for (int j = 0; j < NTC; ++j) acc[i][j] = (f32x4){0.f, 0.f, 0.f, 0.f};

    // staging: 16B chunks; chunk c -> row c>>2, 16B-sub c&3; LDS off = c*16B
    const int s_row = tid >> 2;   // 0..63
    const int s_cc  = tid & 3;

    int rB0 = bn + s_row;
    int rB1 = bn + 64 + s_row;
    if (CLAMPN) { rB0 = min(rB0, N - 1); rB1 = min(rB1, N - 1); }
    const bf16_t* gA0 = A + (size_t)(bm + s_row) * lda + s_cc * 8;
    const bf16_t* gA1 = A + (size_t)(bm + 64 + s_row) * lda + s_cc * 8;
    const bf16_t* gB0 = B + (size_t)rB0 * ldb + s_cc * 8;
    const bf16_t* gB1 = B + (size_t)rB1 * ldb + s_cc * 8;

    bf16_t* dA0 = sA + (size_t)tid * 8;
    bf16_t* dA1 = sA + (size_t)(256 + tid) * 8;
    bf16_t* dB0 = sB + (size_t)tid * 8;
    bf16_t* dB1 = sB + (size_t)(256 + tid) * 8;

    const int mrow = lane & 15;
    const int q    = lane >> 4;

    for (int k0 = 0; k0 < K; k0 += BK) {
        gl_lds16(gA0 + k0, dA0);
        gl_lds16(gA1 + k0, dA1);
        gl_lds16(gB0 + k0, dB0);
        if constexpr (BNT == 128) gl_lds16(gB1 + k0, dB1);
        __syncthreads();   // drains vmcnt(0): DMA complete, tile ready

        int4v af[4], bf[NTC];
        const bf16_t* pa = sA + ((wm * 64 + mrow) * BK + q * 8);
        const bf16_t* pb = sB + ((wn * (BNT / 2) + mrow) * BK + q * 8);
#pragma unroll
        for (int t = 0; t < 4; ++t) af[t] = *(const int4v*)(pa + t * 16 * BK);
#pragma unroll
        for (int t = 0; t < NTC; ++t) bf[t] = *(const int4v*)(pb + t * 16 * BK);
#pragma unroll
        for (int mt = 0; mt < 4; ++mt)
#pragma unroll
            for (int nt = 0; nt < NTC; ++nt)
                acc[mt][nt] = mfma16(af[mt], bf[nt], acc[mt][nt]);
        __syncthreads();   // readers done before next iter's DMA overwrites
    }

    int f = 0;
    if (MODE == 0) f = flag[0];

    // C/D layout: col = lane&15, row = (lane>>4)*4 + r   [m89/m91]
    const int coln = lane & 15;
    const int rq   = lane >> 4;
#pragma unroll
    for (int mt = 0; mt < 4; ++mt) {
#pragma unroll
        for (int r = 0; r < 4; ++r) {
            const int gm = bm + wm * 64 + mt * 16 + rq * 4 + r;
#pragma unroll
            for (int nt = 0; nt < NTC; ++nt) {
                const int gn = bn + wn * (BNT / 2) + nt * 16 + coln;
                const float c = acc[mt][nt][r];
                if (MODE == 0) {
                    if (gn < N) {
                        const size_t xi = (size_t)gm * N + gn;
                        const float xv = f ? ((const float*)Xin)[xi]
                                           : (float)((const bf16_t*)Xin)[xi];
                        Out[(size_t)gm * ldo + gn] = (bf16_t)(xv - c);
                    }
                } else if (MODE == 1) {
                    const size_t idx = (size_t)gm * ldo + gn;
                    const float uo = U[idx];
                    const float ao = fmaxf(uo - 0.3f, 0.0f);
                    const float un = uo + 0.01f * (c + ao - uo);
                    U[idx] = un;
                    Out[idx] = (bf16_t)fmaxf(un - 0.3f, 0.0f);
                } else {
                    if (gn < N)
                        Out[(size_t)gm * ldo + gn] = (bf16_t)c;
                }
            }
        }
    }
}

// fp32-output only: expand a (bf16, d_out scratch) into the fp32 a-region.
// Two passes with disjoint src/dst per pass (expansion-by-2 overlap split).
__global__ void a_move(const bf16_t* __restrict__ src, float* __restrict__ dst,
                       long lo, long hi, const int* __restrict__ flag) {
    if (!flag[0]) return;
    long i = lo + (long)blockIdx.x * 256 + threadIdx.x;
    if (i < hi) dst[i] = (float)src[i];
}

__global__ void recon_out(const bf16_t* __restrict__ rec, void* __restrict__ dout,
                          const int* __restrict__ flag) {
    long i = (long)blockIdx.x * 256 + threadIdx.x;
    if (i >= 6422528L) return;
    if (flag[0]) ((float*)dout)[i] = (float)rec[i];
    else         ((bf16_t*)dout)[i] = rec[i];
}

extern "C" void kernel_launch(void* const* d_in, const int* in_sizes, int n_in,
                              void* d_out, int out_size, void* d_ws, size_t ws_size,
                              hipStream_t stream) {
    const void* x = d_in[0];   // [8192, 784]  fp32 or bf16
    const void* w = d_in[1];   // [784, 2048]  fp32 or bf16
    (void)in_sizes; (void)n_in; (void)out_size; (void)ws_size;

    char* ws = (char*)d_ws;
    float*  u    = (float*)ws;                          // 67,108,864 B
    bf16_t* r    = (bf16_t*)(ws + 67108864);            // 13,107,200 B (8192x800)
    bf16_t* wT   = (bf16_t*)(ws + 80216064);            //  3,276,800 B (2048x800)
    bf16_t* wB   = (bf16_t*)(ws + 83492864);            //  3,211,264 B (784x2048)
    int*    flag = (int*)(ws + 86704128);               // total 86.7 MB
    bf16_t* aA   = (bf16_t*)((char*)d_out + 12845056);  // a scratch = bf16 a-region
    bf16_t* rec  = r;                                   // reuse r for recon temp

    sniff<<<1, 256, 0, stream>>>((const uint16_t*)w, flag);
    fill0<<<16384, 256, 0, stream>>>((int4v*)u, 4194304L);   // u = 0
    fill0<<<3200, 256, 0, stream>>>((int4v*)r, 819200L);     // r = 0 (incl. pad)
    fill0<<<8192, 256, 0, stream>>>((int4v*)aA, 2097152L);   // a = 0
    build_w<<<dim3(4, 2048), 256, 0, stream>>>(w, wT, wB, flag);

    // 99 LCA updates: r = x - a@w^T ; u += 0.01*(r@w + a - u); a = relu(u-0.3)
    for (int i = 0; i < 99; ++i) {
        gemm_nt<0, true, 64><<<dim3(64, 13), 256, 0, stream>>>(
            aA, wB, 784, 2048, 2048, 2048, x, nullptr, r, 800, flag);
        gemm_nt<1, false, 128><<<dim3(64, 16), 256, 0, stream>>>(
            r, wT, 2048, 800, 800, 800, nullptr, u, aA, 2048, flag);
    }

    // reconstruction = a @ w^T -> ws temp (bf16)
    gemm_nt<2, true, 64><<<dim3(64, 13), 256, 0, stream>>>(
        aA, wB, 784, 2048, 2048, 2048, nullptr, nullptr, rec, 784, flag);

    // fp32 out: move a into fp32 a-region (race-free 2-pass split at 5,177,344)
    float* aOutF = (float*)d_out + 6422528;
    a_move<<<45312, 256, 0, stream>>>(aA, aOutF, 5177344L, 16777216L, flag);
    a_move<<<20224, 256, 0, stream>>>(aA, aOutF, 0L, 5177344L, flag);

    // recon -> d_out front, flag dtype (aA scratch dead by now in fp32 mode)
    recon_out<<<25088, 256, 0, stream>>>(rec, d_out, flag);
}